// Round 9
// baseline (394.480 us; speedup 1.0000x reference)
//
#include <hip/hip_runtime.h>
#include <hip/hip_bf16.h>

#define NEG 0.2f
#define BK_SHIFT 9       // 512 nodes per bucket
#define BK_CAP 9216      // slots per bucket (mean ~8192, sigma ~90 -> 11 sigma headroom)

typedef short short8 __attribute__((ext_vector_type(8)));   // 8 bf16 (4 VGPRs)
typedef float f32x4 __attribute__((ext_vector_type(4)));

__device__ __forceinline__ float lrelu(float x){ return x > 0.f ? x : NEG * x; }
// fast elu: expm1f is a slow libm path; __expf is HW v_exp. For x<=0 error ~1e-7.
__device__ __forceinline__ float elu_fast(float x){ return x > 0.f ? x : __expf(x) - 1.f; }
__device__ __forceinline__ unsigned short f2bf(float f){
  unsigned int u = __float_as_uint(f);
  unsigned int r = u + 0x7fffu + ((u >> 16) & 1u);   // round-to-nearest-even
  return (unsigned short)(r >> 16);
}
__device__ __forceinline__ float bf2f(unsigned short u){
  return __uint_as_float(((unsigned int)u) << 16);
}
// one packed uint (2 bf16) -> float2 (x = low half, y = high half)
__device__ __forceinline__ float2 bfu2(unsigned int v){
  float2 r;
  r.x = __uint_as_float(v << 16);
  r.y = __uint_as_float(v & 0xffff0000u);
  return r;
}

// ebuf entry packing: src in bits 0..22, dst_local (9b) in bits 23..31. Valid for N < 2^23.
#define EB_SRC_MASK 0x7fffffu

// ---------------- fused: binA (blocks [0,nA)) || packW (blocks [nA,nA+40)) ----------------
// binA: bin edges into bucket-major ebuf + GLOBAL deg[dst] atomics (replaces csrC's
// LDS-histogram pass; hidden inside this memory-bound kernel).
__global__ __launch_bounds__(512) void k_binA_packW(
    const int* __restrict__ src, const int* __restrict__ dst, int E,
    int* __restrict__ gcursor, int* __restrict__ deg, unsigned int* __restrict__ ebuf,
    const float* __restrict__ W, unsigned short* __restrict__ Wp,
    const float* __restrict__ W2, unsigned short* __restrict__ Wp2, int nA){
  __shared__ int hist[256];
  __shared__ int base[256];
  int t = threadIdx.x;
  int bid = blockIdx.x;
  if (bid >= nA){
    int idx = (bid - nA) * 512 + t;
    if (idx < 16384){                   // W1 pack: Wp[n][k] = W1[k][n]
      int n = idx >> 7, k = idx & 127;
      Wp[n * 128 + k] = f2bf(W[(size_t)k * 128 + n]);
    } else {                            // W2 pack: Wp2[n][k] = W2[k][n], n<32, k<128
      int i2 = idx - 16384;
      int n = i2 >> 7, k = i2 & 127;
      Wp2[n * 128 + k] = f2bf(W2[(size_t)k * 32 + n]);
    }
    return;
  }
  if (t < 256) hist[t] = 0;
  __syncthreads();
  int e0 = bid * 4096;
  int dsr[8], ssr[8];
  #pragma unroll
  for (int j = 0; j < 8; j++){
    int e = e0 + j * 512 + t;
    if (e < E){
      dsr[j] = dst[e]; ssr[j] = src[e];
      atomicAdd(&hist[dsr[j] >> BK_SHIFT], 1);
      atomicAdd(&deg[dsr[j]], 1);       // global degree count (L2-resident, 400KB)
    } else dsr[j] = -1;
  }
  __syncthreads();
  if (t < 256){
    int cnt = hist[t];
    if (cnt > 0) base[t] = atomicAdd(&gcursor[t], cnt);
    hist[t] = 0;                 // reuse as local placement cursor
  }
  __syncthreads();
  #pragma unroll
  for (int j = 0; j < 8; j++){
    if (dsr[j] >= 0){
      int d = dsr[j]; int b = d >> BK_SHIFT;
      int loc = atomicAdd(&hist[b], 1);
      unsigned int dloc = (unsigned int)(d & ((1 << BK_SHIFT) - 1));
      ebuf[(size_t)b * BK_CAP + base[b] + loc] = (unsigned int)ssr[j] | (dloc << 23);
    }
  }
}

// ---------------- fused: scan (blocks [0,NBK), tiny) || gemm1 (blocks [NBK,...)) -------
// scan: per-bucket scan of deg -> rowp + cur (global placement cursors) + self-loop
// write. No ebuf read, no histogram -- ~2us, fully hidden under gemm1.
// gemm1: x[N,128] @ W[128,128] -> h_bf[N,128] bf16, + ss1/sd1 fused.
__global__ __launch_bounds__(256, 3) void k_scan_gemm1(
    const int* __restrict__ gcount, const int* __restrict__ deg,
    int* __restrict__ rowp, int* __restrict__ cur, int* __restrict__ csr,
    int N, int NBK, int total,
    const float* __restrict__ x, const unsigned short* __restrict__ Wp,
    const float* __restrict__ a_src, const float* __restrict__ a_dst,
    unsigned short* __restrict__ h_bf, float* __restrict__ ss, float* __restrict__ sd){
  __shared__ __align__(16) unsigned short Wt[128 * 136];   // gemm: Wt[n][k] | scan: psum/bsum
  __shared__ __align__(16) unsigned short Xb[64 * 136];    // gemm: Xb[row][k]
  int t = threadIdx.x;

  if (blockIdx.x < (unsigned)NBK){
    // ---------- scan body (256 threads, 2 nodes/thread) ----------
    int* psum = (int*)Wt;          // [256]
    int* bsum = psum + 256;        // [256]
    int b = blockIdx.x;
    int nbase = b << BK_SHIFT;
    int bv = 0;
    {
      int nodes = 0;
      if (t < NBK){ int nb = N - (t << BK_SHIFT); nodes = nb > 512 ? 512 : nb; bv = gcount[t] + nodes; }
      bsum[t] = bv;
    }
    int n0 = nbase + 2 * t, n1 = nbase + 2 * t + 1;
    int d0 = (n0 < N) ? deg[n0] : 0;
    int d1 = (n1 < N) ? deg[n1] : 0;
    int ps = d0 + d1;
    psum[t] = ps;
    __syncthreads();
    for (int off = 1; off < 256; off <<= 1){
      int xa = (t >= off) ? bsum[t - off] : 0;
      int xb = (t >= off) ? psum[t - off] : 0;
      __syncthreads();
      bsum[t] += xa; psum[t] += xb;
      __syncthreads();
    }
    int eo = psum[t] - ps;               // exclusive deg-sum at node 2t (local)
    int bb = (b == 0) ? 0 : bsum[b - 1];
    int r0 = bb + eo + 2 * t;            // +2t: one self-loop slot per prior node
    int r1 = bb + eo + d0 + 2 * t + 1;
    if (n0 < N){ rowp[n0] = r0; cur[n0] = r0; csr[r0 + d0] = n0; }
    if (n1 < N){ rowp[n1] = r1; cur[n1] = r1; csr[r1 + d1] = n1; }
    if (b == 0 && t == 0) rowp[N] = total;
    return;
  }

  // ---------- gemm1 body (256 threads, 4 waves) ----------
  int rb = (blockIdx.x - NBK) * 64;

  #pragma unroll
  for (int j = 0; j < 8; j++){
    int fi = j * 256 + t;
    int n = fi >> 4, ch = fi & 15;
    *(uint4*)&Wt[n * 136 + ch * 8] = *(const uint4*)&Wp[n * 128 + ch * 8];
  }
  #pragma unroll
  for (int j = 0; j < 8; j++){
    int fi = j * 256 + t;           // 0..2047
    int row = fi >> 5, k4 = (fi & 31) * 4;
    int gr = rb + row;
    float4 v = make_float4(0.f, 0.f, 0.f, 0.f);
    if (gr < N) v = *(const float4*)&x[(size_t)gr * 128 + k4];
    uint2 pk;
    pk.x = ((unsigned)f2bf(v.y) << 16) | f2bf(v.x);
    pk.y = ((unsigned)f2bf(v.w) << 16) | f2bf(v.z);
    *(uint2*)&Xb[row * 136 + k4] = pk;
  }
  __syncthreads();

  int w = t >> 6, l = t & 63;
  int m = l & 15, quad = l >> 4;
  f32x4 acc[8];
  #pragma unroll
  for (int ct = 0; ct < 8; ct++) acc[ct] = (f32x4){0.f, 0.f, 0.f, 0.f};

  #pragma unroll
  for (int kc = 0; kc < 4; kc++){
    short8 a = *(const short8*)&Xb[(w * 16 + m) * 136 + kc * 32 + quad * 8];
    #pragma unroll
    for (int ct = 0; ct < 8; ct++){
      short8 bfr = *(const short8*)&Wt[(ct * 16 + m) * 136 + kc * 32 + quad * 8];
      acc[ct] = __builtin_amdgcn_mfma_f32_16x16x32_bf16(a, bfr, acc[ct], 0, 0, 0);
    }
  }

  float as[8], ad[8];
  #pragma unroll
  for (int ct = 0; ct < 8; ct++){ as[ct] = a_src[ct * 16 + m]; ad[ct] = a_dst[ct * 16 + m]; }

  #pragma unroll
  for (int reg = 0; reg < 4; reg++){
    int gr = rb + w * 16 + quad * 4 + reg;
    bool ok = gr < N;
    if (ok){
      #pragma unroll
      for (int ct = 0; ct < 8; ct++)
        h_bf[(size_t)gr * 128 + ct * 16 + m] = f2bf(acc[ct][reg]);
    }
    #pragma unroll
    for (int hh = 0; hh < 4; hh++){
      float pss = acc[2*hh][reg] * as[2*hh] + acc[2*hh+1][reg] * as[2*hh+1];
      float pd = acc[2*hh][reg] * ad[2*hh] + acc[2*hh+1][reg] * ad[2*hh+1];
      pss += __shfl_xor(pss, 1, 16); pss += __shfl_xor(pss, 2, 16);
      pss += __shfl_xor(pss, 4, 16); pss += __shfl_xor(pss, 8, 16);
      pd += __shfl_xor(pd, 1, 16); pd += __shfl_xor(pd, 2, 16);
      pd += __shfl_xor(pd, 4, 16); pd += __shfl_xor(pd, 8, 16);
      if (m == 0 && ok){ ss[(size_t)gr * 4 + hh] = pss; sd[(size_t)gr * 4 + hh] = pd; }
    }
  }
}

// ---------------- place: 4 blocks/bucket, global-cursor scatter. ~8 edges/thread at
// full machine width (vs old csrC's 196 blocks x 32 edges/thread serial grind).
__global__ __launch_bounds__(256) void k_place(
    const unsigned int* __restrict__ ebuf, const int* __restrict__ gcount,
    int* __restrict__ cur, int* __restrict__ csr){
  int b = blockIdx.x >> 2;       // bucket
  int h = blockIdx.x & 3;        // quarter
  int cnt = gcount[b];
  int nbase = b << BK_SHIFT;
  const unsigned int* eb = ebuf + (size_t)b * BK_CAP;
  for (int i = h * 256 + threadIdx.x; i < cnt; i += 1024){
    unsigned int e = eb[i];
    int pos = atomicAdd(&cur[nbase + (int)(e >> 23)], 1);
    csr[pos] = (int)(e & EB_SRC_MASK);
  }
}

// ---------------- agg1: 1 wave per node; 16 edges/iter, uint4 gathers (4 rows/instr),
// software-pipelined csr+ss prefetch. Proven 76.5-77.3us (memory-system ceiling).
__global__ __launch_bounds__(256) void k_agg1(
    const int* __restrict__ row_ptr, const int* __restrict__ csr_src,
    const float* __restrict__ ss, const float* __restrict__ sdst,
    const unsigned short* __restrict__ hb,
    unsigned int* __restrict__ out1_bf, int N){
  int n = blockIdx.x * 4 + (threadIdx.x >> 6);
  if (n >= N) return;
  int l = threadIdx.x & 63;
  int q  = (l & 7) + ((l >> 5) << 3);   // weight-edge index 0..15 (dup across bits 3,4)
  int hh = (l >> 3) & 3;                // weight head
  int slot = l >> 4;                    // gather slot 0..3
  int c = l & 15;                       // channel chunk (channels c*8..c*8+7)
  int hd = c >> 2;                      // gather head
  float sdw = sdst[(size_t)n * 4 + hh];
  int beg = row_ptr[n], end = row_ptr[n + 1];

  float acc[8] = {0.f,0.f,0.f,0.f,0.f,0.f,0.f,0.f};
  float swacc = 0.f;

  int e = beg;
  int remaining = end - beg;            // >= 1 (self loop)
  int qc = q < remaining ? q : 0;
  int sj = csr_src[e + qc];
  float sv = ss[(size_t)sj * 4 + hh];

  while (remaining > 0){
    int cur_ = remaining > 16 ? 16 : remaining;
    float wv = (q < cur_) ? __expf(lrelu(sv + sdw)) : 0.f;
    swacc += wv;
    int sjc = sj;
    int rn = remaining - 16;
    if (rn > 0){                        // prefetch next batch's csr + ss
      int qn = q < rn ? q : 0;
      sj = csr_src[e + 16 + qn];
      sv = ss[(size_t)sj * 4 + hh];
    }
    #pragma unroll
    for (int p = 0; p < 4; p++){
      int base_p = ((p & 1) << 2) + ((p >> 1) << 3);    // 0,4,8,12
      if (base_p < cur_){               // wave-uniform whole-pass skip
        int sl = ((p & 1) << 2) + slot + ((p >> 1) << 5);   // lane holding edge base_p+slot
        int s  = __shfl(sjc, sl, 64);
        float w = __shfl(wv, sl + (hd << 3), 64);
        uint4 u = *(const uint4*)&hb[(size_t)s * 128 + (c << 3)];
        float2 f0 = bfu2(u.x), f1 = bfu2(u.y), f2 = bfu2(u.z), f3 = bfu2(u.w);
        acc[0] += w * f0.x; acc[1] += w * f0.y;
        acc[2] += w * f1.x; acc[3] += w * f1.y;
        acc[4] += w * f2.x; acc[5] += w * f2.y;
        acc[6] += w * f3.x; acc[7] += w * f3.y;
      }
    }
    e += 16; remaining = rn;
  }

  // reduce channel accumulators across the 4 gather slots (bits 4,5)
  #pragma unroll
  for (int i = 0; i < 8; i++){
    acc[i] += __shfl_xor(acc[i], 16, 64);
    acc[i] += __shfl_xor(acc[i], 32, 64);
  }
  // reduce weight sums over edges: bits 0..2 + bit 5; bits 3,4 (head) preserved
  swacc += __shfl_xor(swacc, 1, 64);
  swacc += __shfl_xor(swacc, 2, 64);
  swacc += __shfl_xor(swacc, 4, 64);
  swacc += __shfl_xor(swacc, 32, 64);
  float sw = __shfl(swacc, hd << 3, 64);   // lane 8*hd has head-hd sum
  float inv = 1.f / (sw + 1e-16f);
  if (slot == 0){                           // lanes 0..15 write 16B each = 256B row
    unsigned int o0 = ((unsigned)f2bf(acc[1] * inv) << 16) | f2bf(acc[0] * inv);
    unsigned int o1 = ((unsigned)f2bf(acc[3] * inv) << 16) | f2bf(acc[2] * inv);
    unsigned int o2 = ((unsigned)f2bf(acc[5] * inv) << 16) | f2bf(acc[4] * inv);
    unsigned int o3 = ((unsigned)f2bf(acc[7] * inv) << 16) | f2bf(acc[6] * inv);
    uint4 o; o.x = o0; o.y = o1; o.z = o2; o.w = o3;
    *(uint4*)&out1_bf[(size_t)n * 64 + (c << 2)] = o;
  }
}

// ---------------- GEMM2m (MFMA): elu(out1+b1)[N,128] @ W2[128,32] -> h2_bf[N,32] + scores.
// elu+b1 in staging (amortized over dense copy). 128 rows/block.
__global__ __launch_bounds__(256) void k_gemm2m(
    const unsigned int* __restrict__ out1_bf, const float* __restrict__ b1,
    const unsigned short* __restrict__ Wp2,
    const float* __restrict__ a_src, const float* __restrict__ a_dst,
    unsigned short* __restrict__ h2_bf, float* __restrict__ ss2, float* __restrict__ sd2, int N){
  __shared__ __align__(16) unsigned short Wt[32 * 136];    // Wt[n][k] bf16
  __shared__ __align__(16) unsigned short Xb[128 * 136];   // y rows bf16
  int t = threadIdx.x;
  int rb = blockIdx.x * 128;

  #pragma unroll
  for (int j = 0; j < 2; j++){
    int fi = j * 256 + t;              // 0..511
    int n = fi >> 4, ch = fi & 15;
    *(uint4*)&Wt[n * 136 + ch * 8] = *(const uint4*)&Wp2[n * 128 + ch * 8];
  }
  #pragma unroll
  for (int j = 0; j < 8; j++){
    int fi = j * 256 + t;              // 0..2047
    int row = fi >> 4, qq = fi & 15;   // qq: 8-channel group
    int gr = rb + row;
    uint4 o = make_uint4(0u, 0u, 0u, 0u);
    if (gr < N){
      uint4 u = *(const uint4*)&out1_bf[(size_t)gr * 64 + qq * 4];
      float4 bva = *(const float4*)&b1[qq * 8];
      float4 bvb = *(const float4*)&b1[qq * 8 + 4];
      float v0 = elu_fast(bf2f((unsigned short)(u.x & 0xffff)) + bva.x);
      float v1 = elu_fast(bf2f((unsigned short)(u.x >> 16))    + bva.y);
      float v2 = elu_fast(bf2f((unsigned short)(u.y & 0xffff)) + bva.z);
      float v3 = elu_fast(bf2f((unsigned short)(u.y >> 16))    + bva.w);
      float v4 = elu_fast(bf2f((unsigned short)(u.z & 0xffff)) + bvb.x);
      float v5 = elu_fast(bf2f((unsigned short)(u.z >> 16))    + bvb.y);
      float v6 = elu_fast(bf2f((unsigned short)(u.w & 0xffff)) + bvb.z);
      float v7 = elu_fast(bf2f((unsigned short)(u.w >> 16))    + bvb.w);
      o.x = ((unsigned)f2bf(v1) << 16) | f2bf(v0);
      o.y = ((unsigned)f2bf(v3) << 16) | f2bf(v2);
      o.z = ((unsigned)f2bf(v5) << 16) | f2bf(v4);
      o.w = ((unsigned)f2bf(v7) << 16) | f2bf(v6);
    }
    *(uint4*)&Xb[row * 136 + qq * 8] = o;
  }
  __syncthreads();

  int w = t >> 6, l = t & 63;
  int m = l & 15, quad = l >> 4;
  f32x4 acc[2][2];
  #pragma unroll
  for (int rg = 0; rg < 2; rg++){
    acc[rg][0] = (f32x4){0.f, 0.f, 0.f, 0.f};
    acc[rg][1] = (f32x4){0.f, 0.f, 0.f, 0.f};
  }

  #pragma unroll
  for (int kc = 0; kc < 4; kc++){
    #pragma unroll
    for (int ct = 0; ct < 2; ct++){
      short8 bfr = *(const short8*)&Wt[(ct * 16 + m) * 136 + kc * 32 + quad * 8];
      #pragma unroll
      for (int rg = 0; rg < 2; rg++){
        short8 a = *(const short8*)&Xb[(rg * 64 + w * 16 + m) * 136 + kc * 32 + quad * 8];
        acc[rg][ct] = __builtin_amdgcn_mfma_f32_16x16x32_bf16(a, bfr, acc[rg][ct], 0, 0, 0);
      }
    }
  }

  float as0 = a_src[m], as1 = a_src[16 + m];
  float ad0 = a_dst[m], ad1 = a_dst[16 + m];

  #pragma unroll
  for (int rg = 0; rg < 2; rg++){
    #pragma unroll
    for (int reg = 0; reg < 4; reg++){
      int gr = rb + rg * 64 + w * 16 + quad * 4 + reg;
      bool ok = gr < N;
      if (ok){
        h2_bf[(size_t)gr * 32 + m]      = f2bf(acc[rg][0][reg]);
        h2_bf[(size_t)gr * 32 + 16 + m] = f2bf(acc[rg][1][reg]);
      }
      float ps = acc[rg][0][reg] * as0 + acc[rg][1][reg] * as1;
      float pd = acc[rg][0][reg] * ad0 + acc[rg][1][reg] * ad1;
      ps += __shfl_xor(ps, 1, 16); ps += __shfl_xor(ps, 2, 16);
      ps += __shfl_xor(ps, 4, 16); ps += __shfl_xor(ps, 8, 16);
      pd += __shfl_xor(pd, 1, 16); pd += __shfl_xor(pd, 2, 16);
      pd += __shfl_xor(pd, 4, 16); pd += __shfl_xor(pd, 8, 16);
      if (m == 0 && ok){ ss2[gr] = ps; sd2[gr] = pd; }
    }
  }
}

// ---------------- agg2: 1 wave per node; 32 edges/iter, TWO uint4 gathers in flight.
__global__ __launch_bounds__(256) void k_agg2(
    const int* __restrict__ row_ptr, const int* __restrict__ csr_src,
    const float* __restrict__ ss2, const float* __restrict__ sd2,
    const unsigned short* __restrict__ h2bf, const float* __restrict__ b2,
    float* __restrict__ out, int N){
  int n = blockIdx.x * 4 + (threadIdx.x >> 6);
  if (n >= N) return;
  int l = threadIdx.x & 63;
  int q = l & 31;                       // weight-edge index (dup x2 across bit 5)
  int slot = l >> 2;                    // gather edge slot 0..15
  int ch4 = l & 3;                      // 8-channel chunk (16B)
  float sdv = sd2[n];
  int beg = row_ptr[n], end = row_ptr[n + 1];

  float acc[8] = {0.f,0.f,0.f,0.f,0.f,0.f,0.f,0.f};
  float swacc = 0.f;

  int e = beg;
  int remaining = end - beg;
  int qc = q < remaining ? q : 0;
  int sj = csr_src[e + qc];
  float sv = ss2[sj];

  while (remaining > 0){
    int cur_ = remaining > 32 ? 32 : remaining;
    float wv = (q < cur_) ? __expf(lrelu(sv + sdv)) : 0.f;
    swacc += wv;
    int sjc = sj; float wvc = wv;
    int rn = remaining - 32;
    if (rn > 0){
      int qn = q < rn ? q : 0;
      sj = csr_src[e + 32 + qn];
      sv = ss2[sj];
    }
    {                                   // pass 0: edges 0..15 (lane sl holds edge sl)
      int s  = __shfl(sjc, slot, 64);
      float w = __shfl(wvc, slot, 64);
      if (slot < cur_){
        uint4 u = *(const uint4*)&h2bf[(size_t)s * 32 + (ch4 << 3)];
        float2 f0 = bfu2(u.x), f1 = bfu2(u.y), f2 = bfu2(u.z), f3 = bfu2(u.w);
        acc[0] += w * f0.x; acc[1] += w * f0.y;
        acc[2] += w * f1.x; acc[3] += w * f1.y;
        acc[4] += w * f2.x; acc[5] += w * f2.y;
        acc[6] += w * f3.x; acc[7] += w * f3.y;
      }
    }
    if (cur_ > 16){                     // pass 1: edges 16..31 (lane 16+slot holds edge)
      int s  = __shfl(sjc, 16 + slot, 64);
      float w = __shfl(wvc, 16 + slot, 64);
      if (16 + slot < cur_){
        uint4 u = *(const uint4*)&h2bf[(size_t)s * 32 + (ch4 << 3)];
        float2 f0 = bfu2(u.x), f1 = bfu2(u.y), f2 = bfu2(u.z), f3 = bfu2(u.w);
        acc[0] += w * f0.x; acc[1] += w * f0.y;
        acc[2] += w * f1.x; acc[3] += w * f1.y;
        acc[4] += w * f2.x; acc[5] += w * f2.y;
        acc[6] += w * f3.x; acc[7] += w * f3.y;
      }
    }
    e += 32; remaining = rn;
  }

  // reduce channel accumulators across 16 gather slots (bits 2..5)
  #pragma unroll
  for (int i = 0; i < 8; i++){
    acc[i] += __shfl_xor(acc[i], 4, 64);
    acc[i] += __shfl_xor(acc[i], 8, 64);
    acc[i] += __shfl_xor(acc[i], 16, 64);
    acc[i] += __shfl_xor(acc[i], 32, 64);
  }
  // reduce weight sum over 32 edge slots (bits 0..4); dup across bit 5 consistent
  swacc += __shfl_xor(swacc, 1, 64);
  swacc += __shfl_xor(swacc, 2, 64);
  swacc += __shfl_xor(swacc, 4, 64);
  swacc += __shfl_xor(swacc, 8, 64);
  swacc += __shfl_xor(swacc, 16, 64);
  float inv = 1.f / (swacc + 1e-16f);
  if (slot == 0){                        // lanes 0..3 write 32B each = 128B row
    float4 bva = *(const float4*)&b2[(ch4 << 3)];
    float4 bvb = *(const float4*)&b2[(ch4 << 3) + 4];
    float4 oa, ob;
    oa.x = acc[0] * inv + bva.x; oa.y = acc[1] * inv + bva.y;
    oa.z = acc[2] * inv + bva.z; oa.w = acc[3] * inv + bva.w;
    ob.x = acc[4] * inv + bvb.x; ob.y = acc[5] * inv + bvb.y;
    ob.z = acc[6] * inv + bvb.z; ob.w = acc[7] * inv + bvb.w;
    *(float4*)&out[(size_t)n * 32 + (ch4 << 3)] = oa;
    *(float4*)&out[(size_t)n * 32 + (ch4 << 3) + 4] = ob;
  }
}

extern "C" void kernel_launch(void* const* d_in, const int* in_sizes, int n_in,
                              void* d_out, int out_size, void* d_ws, size_t ws_size,
                              hipStream_t stream) {
  const float* x      = (const float*)d_in[0];
  const int*   ei     = (const int*)  d_in[1];
  const float* W1     = (const float*)d_in[2];
  const float* a_src1 = (const float*)d_in[3];
  const float* a_dst1 = (const float*)d_in[4];
  const float* b1     = (const float*)d_in[5];
  const float* W2     = (const float*)d_in[6];
  const float* a_src2 = (const float*)d_in[7];
  const float* a_dst2 = (const float*)d_in[8];
  const float* b2     = (const float*)d_in[9];
  float* out = (float*)d_out;

  int N = in_sizes[0] / 128;
  int E = in_sizes[1] / 2;
  const int* srcp = ei;
  const int* dstp = ei + E;
  int total = E + N;
  int NBK = (N + 511) >> 9;       // buckets of 512 nodes

  char* p = (char*)d_ws;
  auto alloc = [&](size_t bytes) -> void* {
    void* r = (void*)p; p += (bytes + 255) & ~(size_t)255; return r;
  };
  unsigned short* h_bf    = (unsigned short*)alloc((size_t)N * 128 * 2);
  unsigned int*   out1_bf = (unsigned int*)alloc((size_t)N * 64 * 4);   // 128 bf16/row packed as 64 uint
  unsigned short* h2_bf   = (unsigned short*)alloc((size_t)N * 32 * 2);
  unsigned short* Wp      = (unsigned short*)alloc(128 * 128 * 2);
  unsigned short* Wp2     = (unsigned short*)alloc(32 * 128 * 2);
  float* ss1  = (float*)alloc((size_t)N * 4 * 4);
  float* sd1  = (float*)alloc((size_t)N * 4 * 4);
  float* ss2  = (float*)alloc((size_t)N * 4);
  float* sd2  = (float*)alloc((size_t)N * 4);
  int* rowp   = (int*)alloc((size_t)(N + 1) * 4);
  int* csr    = (int*)alloc((size_t)total * 4);
  int* gcur   = (int*)alloc(256 * 4);          // gcur + deg contiguous: one memset
  int* deg    = (int*)alloc((size_t)N * 4);
  int* cur    = (int*)alloc((size_t)N * 4);
  // ebuf (bucket staging, packed uint, 7.2 MB) aliases out1_bf (25.6 MB):
  // disjoint lifetimes (ebuf: binA..place; out1_bf: agg1..gemm2m)
  unsigned int* ebuf = (unsigned int*)out1_bf;
  (void)ws_size; (void)n_in; (void)out_size;

  int nA = (E + 4095) / 4096;
  int nG = (N + 63) / 64;
  int nG2 = (N + 127) / 128;

  hipMemsetAsync(gcur, 0, (size_t)(256 + N) * 4, stream);   // gcur + deg (contiguous)
  k_binA_packW<<<nA + 40, 512, 0, stream>>>(srcp, dstp, E, gcur, deg, ebuf, W1, Wp, W2, Wp2, nA);
  k_scan_gemm1<<<NBK + nG, 256, 0, stream>>>(gcur, deg, rowp, cur, csr, N, NBK, total,
                                             x, Wp, a_src1, a_dst1, h_bf, ss1, sd1);
  k_place<<<NBK * 4, 256, 0, stream>>>(ebuf, gcur, cur, csr);
  k_agg1<<<(N + 3) / 4, 256, 0, stream>>>(rowp, csr, ss1, sd1, h_bf, out1_bf, N);
  k_gemm2m<<<nG2, 256, 0, stream>>>(out1_bf, b1, Wp2, a_src2, a_dst2, h2_bf, ss2, sd2, N);
  k_agg2<<<(N + 3) / 4, 256, 0, stream>>>(rowp, csr, ss2, sd2, h2_bf, b2, out, N);
}

// Round 10
// 291.329 us; speedup vs baseline: 1.3541x; 1.3541x over previous
//
#include <hip/hip_runtime.h>
#include <hip/hip_bf16.h>

#define NEG 0.2f
#define BK_SHIFT 9       // 512 nodes per bucket
#define BK_CAP 9216      // slots per bucket (mean ~8192, sigma ~90 -> 11 sigma headroom)

typedef short short8 __attribute__((ext_vector_type(8)));   // 8 bf16 (4 VGPRs)
typedef float f32x4 __attribute__((ext_vector_type(4)));

__device__ __forceinline__ float lrelu(float x){ return x > 0.f ? x : NEG * x; }
// fast elu: expm1f is a slow libm path; __expf is HW v_exp. For x<=0 error ~1e-7.
__device__ __forceinline__ float elu_fast(float x){ return x > 0.f ? x : __expf(x) - 1.f; }
__device__ __forceinline__ unsigned short f2bf(float f){
  unsigned int u = __float_as_uint(f);
  unsigned int r = u + 0x7fffu + ((u >> 16) & 1u);   // round-to-nearest-even
  return (unsigned short)(r >> 16);
}
__device__ __forceinline__ float bf2f(unsigned short u){
  return __uint_as_float(((unsigned int)u) << 16);
}
// one packed uint (2 bf16) -> float2 (x = low half, y = high half)
__device__ __forceinline__ float2 bfu2(unsigned int v){
  float2 r;
  r.x = __uint_as_float(v << 16);
  r.y = __uint_as_float(v & 0xffff0000u);
  return r;
}

// ebuf entry packing: src in bits 0..22, dst_local (9b) in bits 23..31. Valid for N < 2^23.
#define EB_SRC_MASK 0x7fffffu

// ---------------- fused: binA (blocks [0,nA)) || packW (blocks [nA,nA+40)) ----------------
// NOTE (R9 lesson): do NOT add global deg[dst] atomics here -- 1.6M random-address
// global RMWs serialize at L2 (~50ns each, +50us; VALUBusy collapsed to 1.2%).
__global__ __launch_bounds__(512) void k_binA_packW(
    const int* __restrict__ src, const int* __restrict__ dst, int E,
    int* __restrict__ gcursor, unsigned int* __restrict__ ebuf,
    const float* __restrict__ W, unsigned short* __restrict__ Wp,
    const float* __restrict__ W2, unsigned short* __restrict__ Wp2, int nA){
  __shared__ int hist[256];
  __shared__ int base[256];
  int t = threadIdx.x;
  int bid = blockIdx.x;
  if (bid >= nA){
    int idx = (bid - nA) * 512 + t;
    if (idx < 16384){                   // W1 pack: Wp[n][k] = W1[k][n]
      int n = idx >> 7, k = idx & 127;
      Wp[n * 128 + k] = f2bf(W[(size_t)k * 128 + n]);
    } else {                            // W2 pack: Wp2[n][k] = W2[k][n], n<32, k<128
      int i2 = idx - 16384;
      int n = i2 >> 7, k = i2 & 127;
      Wp2[n * 128 + k] = f2bf(W2[(size_t)k * 32 + n]);
    }
    return;
  }
  if (t < 256) hist[t] = 0;
  __syncthreads();
  int e0 = bid * 4096;
  int dsr[8], ssr[8];
  #pragma unroll
  for (int j = 0; j < 8; j++){
    int e = e0 + j * 512 + t;
    if (e < E){
      dsr[j] = dst[e]; ssr[j] = src[e];
      atomicAdd(&hist[dsr[j] >> BK_SHIFT], 1);
    } else dsr[j] = -1;
  }
  __syncthreads();
  if (t < 256){
    int cnt = hist[t];
    if (cnt > 0) base[t] = atomicAdd(&gcursor[t], cnt);
    hist[t] = 0;                 // reuse as local placement cursor
  }
  __syncthreads();
  #pragma unroll
  for (int j = 0; j < 8; j++){
    if (dsr[j] >= 0){
      int d = dsr[j]; int b = d >> BK_SHIFT;
      int loc = atomicAdd(&hist[b], 1);
      unsigned int dloc = (unsigned int)(d & ((1 << BK_SHIFT) - 1));
      ebuf[(size_t)b * BK_CAP + base[b] + loc] = (unsigned int)ssr[j] | (dloc << 23);
    }
  }
}

// ---------------- fused: csrC (blocks [0,NBK), 256 thr) || gemm1 (blocks [NBK,...)) -------
__global__ __launch_bounds__(256, 3) void k_csrC_gemm1(
    const unsigned int* __restrict__ ebuf, const int* __restrict__ gcount,
    int* __restrict__ rowp, int* __restrict__ csr, int N, int NBK, int total,
    const float* __restrict__ x, const unsigned short* __restrict__ Wp,
    const float* __restrict__ a_src, const float* __restrict__ a_dst,
    unsigned short* __restrict__ h_bf, float* __restrict__ ss, float* __restrict__ sd){
  __shared__ __align__(16) unsigned short Wt[128 * 136];   // gemm: Wt[n][k] | csrC: hist/psum/bsum
  __shared__ __align__(16) unsigned short Xb[64 * 136];    // gemm: Xb[row][k]
  int t = threadIdx.x;

  if (blockIdx.x < (unsigned)NBK){
    // ---------- csrC body (256 threads) ----------
    int* hist = (int*)Wt;          // [512]
    int* psum = hist + 512;        // [256]
    int* bsum = psum + 256;        // [256]
    int b = blockIdx.x;
    int nbase = b << BK_SHIFT;
    int cnt = gcount[b];
    const unsigned int* eb = ebuf + (size_t)b * BK_CAP;
    hist[t] = 0; hist[t + 256] = 0;
    int bv = 0;
    {
      int nodes = 0;
      if (t < NBK){ int nb = N - (t << BK_SHIFT); nodes = nb > 512 ? 512 : nb; bv = gcount[t] + nodes; }
      bsum[t] = bv;
    }
    __syncthreads();
    for (int off = 1; off < 256; off <<= 1){
      int xv = (t >= off) ? bsum[t - off] : 0;
      __syncthreads();
      bsum[t] += xv;
      __syncthreads();
    }
    for (int i = t; i < cnt; i += 256)
      atomicAdd(&hist[eb[i] >> 23], 1);
    __syncthreads();
    int v0 = hist[2 * t], v1 = hist[2 * t + 1];
    int ps = v0 + v1;
    psum[t] = ps;
    __syncthreads();
    for (int off = 1; off < 256; off <<= 1){
      int xv = (t >= off) ? psum[t - off] : 0;
      __syncthreads();
      psum[t] += xv;
      __syncthreads();
    }
    {
      int eo = psum[t] - ps;               // exclusive deg-sum at node 2t
      int bb = (b == 0) ? 0 : bsum[b - 1];
      int n0 = 2 * t, n1 = 2 * t + 1;
      int r0 = bb + eo + n0;               // +n0: one self-loop slot per prior node
      int r1 = bb + eo + v0 + n1;
      if (nbase + n0 < N) rowp[nbase + n0] = r0;
      if (nbase + n1 < N) rowp[nbase + n1] = r1;
      hist[n0] = r0; hist[n1] = r1;        // reuse as cursors
    }
    if (b == 0 && t == 0) rowp[N] = total;
    __syncthreads();
    for (int i = t; i < cnt; i += 256){
      unsigned int e = eb[i];
      int pos = atomicAdd(&hist[e >> 23], 1);
      csr[pos] = (int)(e & EB_SRC_MASK);
    }
    __syncthreads();
    {
      int n0 = 2 * t, n1 = 2 * t + 1;
      if (nbase + n0 < N) csr[hist[n0]] = nbase + n0;
      if (nbase + n1 < N) csr[hist[n1]] = nbase + n1;
    }
    return;
  }

  // ---------- gemm1 body (256 threads, 4 waves) ----------
  int rb = (blockIdx.x - NBK) * 64;

  #pragma unroll
  for (int j = 0; j < 8; j++){
    int fi = j * 256 + t;
    int n = fi >> 4, ch = fi & 15;
    *(uint4*)&Wt[n * 136 + ch * 8] = *(const uint4*)&Wp[n * 128 + ch * 8];
  }
  #pragma unroll
  for (int j = 0; j < 8; j++){
    int fi = j * 256 + t;           // 0..2047
    int row = fi >> 5, k4 = (fi & 31) * 4;
    int gr = rb + row;
    float4 v = make_float4(0.f, 0.f, 0.f, 0.f);
    if (gr < N) v = *(const float4*)&x[(size_t)gr * 128 + k4];
    uint2 pk;
    pk.x = ((unsigned)f2bf(v.y) << 16) | f2bf(v.x);
    pk.y = ((unsigned)f2bf(v.w) << 16) | f2bf(v.z);
    *(uint2*)&Xb[row * 136 + k4] = pk;
  }
  __syncthreads();

  int w = t >> 6, l = t & 63;
  int m = l & 15, quad = l >> 4;
  f32x4 acc[8];
  #pragma unroll
  for (int ct = 0; ct < 8; ct++) acc[ct] = (f32x4){0.f, 0.f, 0.f, 0.f};

  #pragma unroll
  for (int kc = 0; kc < 4; kc++){
    short8 a = *(const short8*)&Xb[(w * 16 + m) * 136 + kc * 32 + quad * 8];
    #pragma unroll
    for (int ct = 0; ct < 8; ct++){
      short8 bfr = *(const short8*)&Wt[(ct * 16 + m) * 136 + kc * 32 + quad * 8];
      acc[ct] = __builtin_amdgcn_mfma_f32_16x16x32_bf16(a, bfr, acc[ct], 0, 0, 0);
    }
  }

  float as[8], ad[8];
  #pragma unroll
  for (int ct = 0; ct < 8; ct++){ as[ct] = a_src[ct * 16 + m]; ad[ct] = a_dst[ct * 16 + m]; }

  #pragma unroll
  for (int reg = 0; reg < 4; reg++){
    int gr = rb + w * 16 + quad * 4 + reg;
    bool ok = gr < N;
    if (ok){
      #pragma unroll
      for (int ct = 0; ct < 8; ct++)
        h_bf[(size_t)gr * 128 + ct * 16 + m] = f2bf(acc[ct][reg]);
    }
    #pragma unroll
    for (int hh = 0; hh < 4; hh++){
      float pss = acc[2*hh][reg] * as[2*hh] + acc[2*hh+1][reg] * as[2*hh+1];
      float pd = acc[2*hh][reg] * ad[2*hh] + acc[2*hh+1][reg] * ad[2*hh+1];
      pss += __shfl_xor(pss, 1, 16); pss += __shfl_xor(pss, 2, 16);
      pss += __shfl_xor(pss, 4, 16); pss += __shfl_xor(pss, 8, 16);
      pd += __shfl_xor(pd, 1, 16); pd += __shfl_xor(pd, 2, 16);
      pd += __shfl_xor(pd, 4, 16); pd += __shfl_xor(pd, 8, 16);
      if (m == 0 && ok){ ss[(size_t)gr * 4 + hh] = pss; sd[(size_t)gr * 4 + hh] = pd; }
    }
  }
}

// ---------------- agg1: 1 wave per node; 16 edges/iter, uint4 gathers (4 rows/instr),
// software-pipelined csr+ss prefetch. Proven 76.5-77.3us (memory-system ceiling:
// ~475MB demand / 77us = 6.1 TB/s at L2 interface, ~97% of achievable).
__global__ __launch_bounds__(256) void k_agg1(
    const int* __restrict__ row_ptr, const int* __restrict__ csr_src,
    const float* __restrict__ ss, const float* __restrict__ sdst,
    const unsigned short* __restrict__ hb,
    unsigned int* __restrict__ out1_bf, int N){
  int n = blockIdx.x * 4 + (threadIdx.x >> 6);
  if (n >= N) return;
  int l = threadIdx.x & 63;
  int q  = (l & 7) + ((l >> 5) << 3);   // weight-edge index 0..15 (dup across bits 3,4)
  int hh = (l >> 3) & 3;                // weight head
  int slot = l >> 4;                    // gather slot 0..3
  int c = l & 15;                       // channel chunk (channels c*8..c*8+7)
  int hd = c >> 2;                      // gather head
  float sdw = sdst[(size_t)n * 4 + hh];
  int beg = row_ptr[n], end = row_ptr[n + 1];

  float acc[8] = {0.f,0.f,0.f,0.f,0.f,0.f,0.f,0.f};
  float swacc = 0.f;

  int e = beg;
  int remaining = end - beg;            // >= 1 (self loop)
  int qc = q < remaining ? q : 0;
  int sj = csr_src[e + qc];
  float sv = ss[(size_t)sj * 4 + hh];

  while (remaining > 0){
    int cur = remaining > 16 ? 16 : remaining;
    float wv = (q < cur) ? __expf(lrelu(sv + sdw)) : 0.f;
    swacc += wv;
    int sjc = sj;
    int rn = remaining - 16;
    if (rn > 0){                        // prefetch next batch's csr + ss
      int qn = q < rn ? q : 0;
      sj = csr_src[e + 16 + qn];
      sv = ss[(size_t)sj * 4 + hh];
    }
    #pragma unroll
    for (int p = 0; p < 4; p++){
      int base_p = ((p & 1) << 2) + ((p >> 1) << 3);    // 0,4,8,12
      if (base_p < cur){                // wave-uniform whole-pass skip
        int sl = ((p & 1) << 2) + slot + ((p >> 1) << 5);   // lane holding edge base_p+slot
        int s  = __shfl(sjc, sl, 64);
        float w = __shfl(wv, sl + (hd << 3), 64);
        uint4 u = *(const uint4*)&hb[(size_t)s * 128 + (c << 3)];
        float2 f0 = bfu2(u.x), f1 = bfu2(u.y), f2 = bfu2(u.z), f3 = bfu2(u.w);
        acc[0] += w * f0.x; acc[1] += w * f0.y;
        acc[2] += w * f1.x; acc[3] += w * f1.y;
        acc[4] += w * f2.x; acc[5] += w * f2.y;
        acc[6] += w * f3.x; acc[7] += w * f3.y;
      }
    }
    e += 16; remaining = rn;
  }

  // reduce channel accumulators across the 4 gather slots (bits 4,5)
  #pragma unroll
  for (int i = 0; i < 8; i++){
    acc[i] += __shfl_xor(acc[i], 16, 64);
    acc[i] += __shfl_xor(acc[i], 32, 64);
  }
  // reduce weight sums over edges: bits 0..2 + bit 5; bits 3,4 (head) preserved
  swacc += __shfl_xor(swacc, 1, 64);
  swacc += __shfl_xor(swacc, 2, 64);
  swacc += __shfl_xor(swacc, 4, 64);
  swacc += __shfl_xor(swacc, 32, 64);
  float sw = __shfl(swacc, hd << 3, 64);   // lane 8*hd has head-hd sum
  float inv = 1.f / (sw + 1e-16f);
  if (slot == 0){                           // lanes 0..15 write 16B each = 256B row
    unsigned int o0 = ((unsigned)f2bf(acc[1] * inv) << 16) | f2bf(acc[0] * inv);
    unsigned int o1 = ((unsigned)f2bf(acc[3] * inv) << 16) | f2bf(acc[2] * inv);
    unsigned int o2 = ((unsigned)f2bf(acc[5] * inv) << 16) | f2bf(acc[4] * inv);
    unsigned int o3 = ((unsigned)f2bf(acc[7] * inv) << 16) | f2bf(acc[6] * inv);
    uint4 o; o.x = o0; o.y = o1; o.z = o2; o.w = o3;
    *(uint4*)&out1_bf[(size_t)n * 64 + (c << 2)] = o;
  }
}

// ---------------- GEMM2m (MFMA): elu(out1+b1)[N,128] @ W2[128,32] -> h2_bf[N,32] + scores.
// elu+b1 in staging (amortized over dense copy; in agg1's epilogue it cost 5us -- R7).
// 128 rows/block: half the blocks, 2x W2-stage reuse.
__global__ __launch_bounds__(256) void k_gemm2m(
    const unsigned int* __restrict__ out1_bf, const float* __restrict__ b1,
    const unsigned short* __restrict__ Wp2,
    const float* __restrict__ a_src, const float* __restrict__ a_dst,
    unsigned short* __restrict__ h2_bf, float* __restrict__ ss2, float* __restrict__ sd2, int N){
  __shared__ __align__(16) unsigned short Wt[32 * 136];    // Wt[n][k] bf16
  __shared__ __align__(16) unsigned short Xb[128 * 136];   // y rows bf16
  int t = threadIdx.x;
  int rb = blockIdx.x * 128;

  // stage W2' (8 KB): 512 uint4-chunks, 2 per thread
  #pragma unroll
  for (int j = 0; j < 2; j++){
    int fi = j * 256 + t;              // 0..511
    int n = fi >> 4, ch = fi & 15;
    *(uint4*)&Wt[n * 136 + ch * 8] = *(const uint4*)&Wp2[n * 128 + ch * 8];
  }
  // stage y = elu_fast(out1 + b1) as bf16: 128 rows x 16 chunks of 8 ch = 2048 items
  #pragma unroll
  for (int j = 0; j < 8; j++){
    int fi = j * 256 + t;              // 0..2047
    int row = fi >> 4, qq = fi & 15;   // qq: 8-channel group
    int gr = rb + row;
    uint4 o = make_uint4(0u, 0u, 0u, 0u);
    if (gr < N){
      uint4 u = *(const uint4*)&out1_bf[(size_t)gr * 64 + qq * 4];
      float4 bva = *(const float4*)&b1[qq * 8];
      float4 bvb = *(const float4*)&b1[qq * 8 + 4];
      float v0 = elu_fast(bf2f((unsigned short)(u.x & 0xffff)) + bva.x);
      float v1 = elu_fast(bf2f((unsigned short)(u.x >> 16))    + bva.y);
      float v2 = elu_fast(bf2f((unsigned short)(u.y & 0xffff)) + bva.z);
      float v3 = elu_fast(bf2f((unsigned short)(u.y >> 16))    + bva.w);
      float v4 = elu_fast(bf2f((unsigned short)(u.z & 0xffff)) + bvb.x);
      float v5 = elu_fast(bf2f((unsigned short)(u.z >> 16))    + bvb.y);
      float v6 = elu_fast(bf2f((unsigned short)(u.w & 0xffff)) + bvb.z);
      float v7 = elu_fast(bf2f((unsigned short)(u.w >> 16))    + bvb.w);
      o.x = ((unsigned)f2bf(v1) << 16) | f2bf(v0);
      o.y = ((unsigned)f2bf(v3) << 16) | f2bf(v2);
      o.z = ((unsigned)f2bf(v5) << 16) | f2bf(v4);
      o.w = ((unsigned)f2bf(v7) << 16) | f2bf(v6);
    }
    *(uint4*)&Xb[row * 136 + qq * 8] = o;
  }
  __syncthreads();

  int w = t >> 6, l = t & 63;
  int m = l & 15, quad = l >> 4;
  f32x4 acc[2][2];
  #pragma unroll
  for (int rg = 0; rg < 2; rg++){
    acc[rg][0] = (f32x4){0.f, 0.f, 0.f, 0.f};
    acc[rg][1] = (f32x4){0.f, 0.f, 0.f, 0.f};
  }

  #pragma unroll
  for (int kc = 0; kc < 4; kc++){
    #pragma unroll
    for (int ct = 0; ct < 2; ct++){
      short8 bfr = *(const short8*)&Wt[(ct * 16 + m) * 136 + kc * 32 + quad * 8];
      #pragma unroll
      for (int rg = 0; rg < 2; rg++){
        short8 a = *(const short8*)&Xb[(rg * 64 + w * 16 + m) * 136 + kc * 32 + quad * 8];
        acc[rg][ct] = __builtin_amdgcn_mfma_f32_16x16x32_bf16(a, bfr, acc[rg][ct], 0, 0, 0);
      }
    }
  }

  float as0 = a_src[m], as1 = a_src[16 + m];
  float ad0 = a_dst[m], ad1 = a_dst[16 + m];

  #pragma unroll
  for (int rg = 0; rg < 2; rg++){
    #pragma unroll
    for (int reg = 0; reg < 4; reg++){
      int gr = rb + rg * 64 + w * 16 + quad * 4 + reg;
      bool ok = gr < N;
      if (ok){
        h2_bf[(size_t)gr * 32 + m]      = f2bf(acc[rg][0][reg]);
        h2_bf[(size_t)gr * 32 + 16 + m] = f2bf(acc[rg][1][reg]);
      }
      float ps = acc[rg][0][reg] * as0 + acc[rg][1][reg] * as1;
      float pd = acc[rg][0][reg] * ad0 + acc[rg][1][reg] * ad1;
      ps += __shfl_xor(ps, 1, 16); ps += __shfl_xor(ps, 2, 16);
      ps += __shfl_xor(ps, 4, 16); ps += __shfl_xor(ps, 8, 16);
      pd += __shfl_xor(pd, 1, 16); pd += __shfl_xor(pd, 2, 16);
      pd += __shfl_xor(pd, 4, 16); pd += __shfl_xor(pd, 8, 16);
      if (m == 0 && ok){ ss2[gr] = ps; sd2[gr] = pd; }
    }
  }
}

// ---------------- agg2: 1 wave per node; 32 edges/iter, TWO uint4 gathers in flight.
// Halves dependent rounds vs 16/iter (mean deg 17 -> mostly single-round).
__global__ __launch_bounds__(256) void k_agg2(
    const int* __restrict__ row_ptr, const int* __restrict__ csr_src,
    const float* __restrict__ ss2, const float* __restrict__ sd2,
    const unsigned short* __restrict__ h2bf, const float* __restrict__ b2,
    float* __restrict__ out, int N){
  int n = blockIdx.x * 4 + (threadIdx.x >> 6);
  if (n >= N) return;
  int l = threadIdx.x & 63;
  int q = l & 31;                       // weight-edge index (dup x2 across bit 5)
  int slot = l >> 2;                    // gather edge slot 0..15
  int ch4 = l & 3;                      // 8-channel chunk (16B)
  float sdv = sd2[n];
  int beg = row_ptr[n], end = row_ptr[n + 1];

  float acc[8] = {0.f,0.f,0.f,0.f,0.f,0.f,0.f,0.f};
  float swacc = 0.f;

  int e = beg;
  int remaining = end - beg;
  int qc = q < remaining ? q : 0;
  int sj = csr_src[e + qc];
  float sv = ss2[sj];

  while (remaining > 0){
    int cur = remaining > 32 ? 32 : remaining;
    float wv = (q < cur) ? __expf(lrelu(sv + sdv)) : 0.f;
    swacc += wv;
    int sjc = sj; float wvc = wv;
    int rn = remaining - 32;
    if (rn > 0){
      int qn = q < rn ? q : 0;
      sj = csr_src[e + 32 + qn];
      sv = ss2[sj];
    }
    {                                   // pass 0: edges 0..15 (lane sl holds edge sl)
      int s  = __shfl(sjc, slot, 64);
      float w = __shfl(wvc, slot, 64);
      if (slot < cur){
        uint4 u = *(const uint4*)&h2bf[(size_t)s * 32 + (ch4 << 3)];
        float2 f0 = bfu2(u.x), f1 = bfu2(u.y), f2 = bfu2(u.z), f3 = bfu2(u.w);
        acc[0] += w * f0.x; acc[1] += w * f0.y;
        acc[2] += w * f1.x; acc[3] += w * f1.y;
        acc[4] += w * f2.x; acc[5] += w * f2.y;
        acc[6] += w * f3.x; acc[7] += w * f3.y;
      }
    }
    if (cur > 16){                      // pass 1: edges 16..31 (lane 16+slot holds edge)
      int s  = __shfl(sjc, 16 + slot, 64);
      float w = __shfl(wvc, 16 + slot, 64);
      if (16 + slot < cur){
        uint4 u = *(const uint4*)&h2bf[(size_t)s * 32 + (ch4 << 3)];
        float2 f0 = bfu2(u.x), f1 = bfu2(u.y), f2 = bfu2(u.z), f3 = bfu2(u.w);
        acc[0] += w * f0.x; acc[1] += w * f0.y;
        acc[2] += w * f1.x; acc[3] += w * f1.y;
        acc[4] += w * f2.x; acc[5] += w * f2.y;
        acc[6] += w * f3.x; acc[7] += w * f3.y;
      }
    }
    e += 32; remaining = rn;
  }

  // reduce channel accumulators across 16 gather slots (bits 2..5)
  #pragma unroll
  for (int i = 0; i < 8; i++){
    acc[i] += __shfl_xor(acc[i], 4, 64);
    acc[i] += __shfl_xor(acc[i], 8, 64);
    acc[i] += __shfl_xor(acc[i], 16, 64);
    acc[i] += __shfl_xor(acc[i], 32, 64);
  }
  // reduce weight sum over 32 edge slots (bits 0..4); dup across bit 5 consistent
  swacc += __shfl_xor(swacc, 1, 64);
  swacc += __shfl_xor(swacc, 2, 64);
  swacc += __shfl_xor(swacc, 4, 64);
  swacc += __shfl_xor(swacc, 8, 64);
  swacc += __shfl_xor(swacc, 16, 64);
  float inv = 1.f / (swacc + 1e-16f);
  if (slot == 0){                        // lanes 0..3 write 32B each = 128B row
    float4 bva = *(const float4*)&b2[(ch4 << 3)];
    float4 bvb = *(const float4*)&b2[(ch4 << 3) + 4];
    float4 oa, ob;
    oa.x = acc[0] * inv + bva.x; oa.y = acc[1] * inv + bva.y;
    oa.z = acc[2] * inv + bva.z; oa.w = acc[3] * inv + bva.w;
    ob.x = acc[4] * inv + bvb.x; ob.y = acc[5] * inv + bvb.y;
    ob.z = acc[6] * inv + bvb.z; ob.w = acc[7] * inv + bvb.w;
    *(float4*)&out[(size_t)n * 32 + (ch4 << 3)] = oa;
    *(float4*)&out[(size_t)n * 32 + (ch4 << 3) + 4] = ob;
  }
}

extern "C" void kernel_launch(void* const* d_in, const int* in_sizes, int n_in,
                              void* d_out, int out_size, void* d_ws, size_t ws_size,
                              hipStream_t stream) {
  const float* x      = (const float*)d_in[0];
  const int*   ei     = (const int*)  d_in[1];
  const float* W1     = (const float*)d_in[2];
  const float* a_src1 = (const float*)d_in[3];
  const float* a_dst1 = (const float*)d_in[4];
  const float* b1     = (const float*)d_in[5];
  const float* W2     = (const float*)d_in[6];
  const float* a_src2 = (const float*)d_in[7];
  const float* a_dst2 = (const float*)d_in[8];
  const float* b2     = (const float*)d_in[9];
  float* out = (float*)d_out;

  int N = in_sizes[0] / 128;
  int E = in_sizes[1] / 2;
  const int* srcp = ei;
  const int* dstp = ei + E;
  int total = E + N;
  int NBK = (N + 511) >> 9;       // buckets of 512 nodes

  char* p = (char*)d_ws;
  auto alloc = [&](size_t bytes) -> void* {
    void* r = (void*)p; p += (bytes + 255) & ~(size_t)255; return r;
  };
  unsigned short* h_bf    = (unsigned short*)alloc((size_t)N * 128 * 2);
  unsigned int*   out1_bf = (unsigned int*)alloc((size_t)N * 64 * 4);   // 128 bf16/row packed as 64 uint
  unsigned short* h2_bf   = (unsigned short*)alloc((size_t)N * 32 * 2);
  unsigned short* Wp      = (unsigned short*)alloc(128 * 128 * 2);
  unsigned short* Wp2     = (unsigned short*)alloc(32 * 128 * 2);
  float* ss1  = (float*)alloc((size_t)N * 4 * 4);
  float* sd1  = (float*)alloc((size_t)N * 4 * 4);
  float* ss2  = (float*)alloc((size_t)N * 4);
  float* sd2  = (float*)alloc((size_t)N * 4);
  int* rowp   = (int*)alloc((size_t)(N + 1) * 4);
  int* csr    = (int*)alloc((size_t)total * 4);
  int* gcur   = (int*)alloc(256 * 4);
  // ebuf (bucket staging, packed uint, 7.2 MB) aliases out1_bf (25.6 MB): disjoint lifetimes
  unsigned int* ebuf = (unsigned int*)out1_bf;
  (void)ws_size; (void)n_in; (void)out_size;

  int nA = (E + 4095) / 4096;
  int nG = (N + 63) / 64;
  int nG2 = (N + 127) / 128;

  hipMemsetAsync(gcur, 0, 256 * 4, stream);
  k_binA_packW<<<nA + 40, 512, 0, stream>>>(srcp, dstp, E, gcur, ebuf, W1, Wp, W2, Wp2, nA);
  k_csrC_gemm1<<<NBK + nG, 256, 0, stream>>>(ebuf, gcur, rowp, csr, N, NBK, total,
                                             x, Wp, a_src1, a_dst1, h_bf, ss1, sd1);
  k_agg1<<<(N + 3) / 4, 256, 0, stream>>>(rowp, csr, ss1, sd1, h_bf, out1_bf, N);
  k_gemm2m<<<nG2, 256, 0, stream>>>(out1_bf, b1, Wp2, a_src2, a_dst2, h2_bf, ss2, sd2, N);
  k_agg2<<<(N + 3) / 4, 256, 0, stream>>>(rowp, csr, ss2, sd2, h2_bf, b2, out, N);
}